// Round 1
// baseline (28.987 us; speedup 1.0000x reference)
//
#include <hip/hip_runtime.h>

// Problem: S=8192, H=2048
// energies = enc @ (W^T h) + (b . h);  out = softmax(energies)
// ws layout (floats): part[32*2048] | v[2048] | e[8192] | c[1]

#define Hdim 2048
#define Sdim 8192
#define KCHUNKS 32
#define KROWS 64  // Hdim / KCHUNKS

__global__ void k1_partial(const float* __restrict__ W, const float* __restrict__ hid,
                           float* __restrict__ part) {
    // grid (2, 32), block 256. Each thread: 4 consecutive columns, 64 rows.
    int t = threadIdx.x;
    int colBase = blockIdx.x * 1024 + t * 4;
    int k0 = blockIdx.y * KROWS;
    float4 acc = {0.f, 0.f, 0.f, 0.f};
    for (int i = 0; i < KROWS; ++i) {
        int k = k0 + i;
        float hk = hid[k];
        float4 w = *reinterpret_cast<const float4*>(W + (size_t)k * Hdim + colBase);
        acc.x += w.x * hk;
        acc.y += w.y * hk;
        acc.z += w.z * hk;
        acc.w += w.w * hk;
    }
    *reinterpret_cast<float4*>(part + (size_t)blockIdx.y * Hdim + colBase) = acc;
}

__global__ void k1b_reduce(const float* __restrict__ part, const float* __restrict__ b,
                           const float* __restrict__ hid, float* __restrict__ v,
                           float* __restrict__ c) {
    // blocks 0..7: reduce 32 partials per column. block 8: c = dot(b, hid).
    if (blockIdx.x < 8) {
        int h = blockIdx.x * 256 + threadIdx.x;
        float s = 0.f;
#pragma unroll
        for (int j = 0; j < KCHUNKS; ++j) s += part[j * Hdim + h];
        v[h] = s;
    } else {
        __shared__ float red[256];
        float s = 0.f;
        for (int k = threadIdx.x; k < Hdim; k += 256) s += b[k] * hid[k];
        red[threadIdx.x] = s;
        __syncthreads();
        for (int off = 128; off > 0; off >>= 1) {
            if (threadIdx.x < off) red[threadIdx.x] += red[threadIdx.x + off];
            __syncthreads();
        }
        if (threadIdx.x == 0) *c = red[0];
    }
}

__global__ void k2_energies(const float* __restrict__ enc, const float* __restrict__ v,
                            const float* __restrict__ c, float* __restrict__ e) {
    // 4 waves/block, one row per wave. 2048 floats/row = 8 x float4 per lane.
    int wave = threadIdx.x >> 6;
    int lane = threadIdx.x & 63;
    int s = blockIdx.x * 4 + wave;
    const float* row = enc + (size_t)s * Hdim;
    float acc = 0.f;
#pragma unroll
    for (int i = 0; i < 8; ++i) {
        int idx = i * 256 + lane * 4;
        float4 a = *reinterpret_cast<const float4*>(row + idx);
        float4 w = *reinterpret_cast<const float4*>(v + idx);
        acc += a.x * w.x + a.y * w.y + a.z * w.z + a.w * w.w;
    }
#pragma unroll
    for (int off = 32; off > 0; off >>= 1) acc += __shfl_xor(acc, off, 64);
    if (lane == 0) e[s] = acc + *c;
}

__global__ void k3_softmax(const float* __restrict__ e, float* __restrict__ out) {
    // 1 block, 1024 threads, 8 elems each.
    __shared__ float red[16];
    __shared__ float bcast;
    int t = threadIdx.x;
    int lane = t & 63, wid = t >> 6;
    float4 a = *reinterpret_cast<const float4*>(e + t * 8);
    float4 bq = *reinterpret_cast<const float4*>(e + t * 8 + 4);
    float vals[8] = {a.x, a.y, a.z, a.w, bq.x, bq.y, bq.z, bq.w};
    float m = vals[0];
#pragma unroll
    for (int i = 1; i < 8; ++i) m = fmaxf(m, vals[i]);
#pragma unroll
    for (int off = 32; off > 0; off >>= 1) m = fmaxf(m, __shfl_xor(m, off, 64));
    if (lane == 0) red[wid] = m;
    __syncthreads();
    if (wid == 0) {
        float mm = (lane < 16) ? red[lane] : -1e30f;
#pragma unroll
        for (int off = 8; off > 0; off >>= 1) mm = fmaxf(mm, __shfl_xor(mm, off, 64));
        if (lane == 0) bcast = mm;
    }
    __syncthreads();
    m = bcast;
    float ex[8];
    float s = 0.f;
#pragma unroll
    for (int i = 0; i < 8; ++i) {
        ex[i] = __expf(vals[i] - m);
        s += ex[i];
    }
#pragma unroll
    for (int off = 32; off > 0; off >>= 1) s += __shfl_xor(s, off, 64);
    __syncthreads();
    if (lane == 0) red[wid] = s;
    __syncthreads();
    if (wid == 0) {
        float ss = (lane < 16) ? red[lane] : 0.f;
#pragma unroll
        for (int off = 8; off > 0; off >>= 1) ss += __shfl_xor(ss, off, 64);
        if (lane == 0) bcast = ss;
    }
    __syncthreads();
    float inv = 1.0f / bcast;
    float4 o1 = {ex[0] * inv, ex[1] * inv, ex[2] * inv, ex[3] * inv};
    float4 o2 = {ex[4] * inv, ex[5] * inv, ex[6] * inv, ex[7] * inv};
    *reinterpret_cast<float4*>(out + t * 8) = o1;
    *reinterpret_cast<float4*>(out + t * 8 + 4) = o2;
}

extern "C" void kernel_launch(void* const* d_in, const int* in_sizes, int n_in,
                              void* d_out, int out_size, void* d_ws, size_t ws_size,
                              hipStream_t stream) {
    const float* hid = (const float*)d_in[0];   // (1, H)
    const float* enc = (const float*)d_in[1];   // (S, 1, H)
    const float* W   = (const float*)d_in[2];   // (H, H)
    const float* b   = (const float*)d_in[3];   // (H,)
    float* out = (float*)d_out;                 // (1,1,S) = S floats
    float* ws = (float*)d_ws;

    float* part = ws;                        // 32*2048
    float* v    = part + KCHUNKS * Hdim;     // 2048
    float* e    = v + Hdim;                  // 8192
    float* c    = e + Sdim;                  // 1

    k1_partial<<<dim3(2, KCHUNKS), 256, 0, stream>>>(W, hid, part);
    k1b_reduce<<<9, 256, 0, stream>>>(part, b, hid, v, c);
    k2_energies<<<Sdim / 4, 256, 0, stream>>>(enc, v, c, e);
    k3_softmax<<<1, 1024, 0, stream>>>(e, out);
}